// Round 1
// baseline (259.656 us; speedup 1.0000x reference)
//
#include <hip/hip_runtime.h>
#include <hip/hip_bf16.h>
#include <cstdint>

typedef __bf16 bf16x8 __attribute__((ext_vector_type(8)));
typedef float f32x4 __attribute__((ext_vector_type(4)));

#define MFMA16(a, b, c) __builtin_amdgcn_mfma_f32_16x16x32_bf16((a), (b), (c), 0, 0, 0)

// ---------- helpers ----------
__device__ __forceinline__ unsigned short f2bf(float f) {
  union { float f; unsigned u; } v; v.f = f;
  unsigned u = v.u;
  u += 0x7fffu + ((u >> 16) & 1u);   // round-to-nearest-even (finite data only)
  return (unsigned short)(u >> 16);
}
__device__ __forceinline__ unsigned pk2(float a, float b) {
  return (unsigned)f2bf(a) | ((unsigned)f2bf(b) << 16);
}

// ---------- kernel 1: W [1024][128] f32 -> Wt bf16 [3][128][1024] (n-major) ----------
__global__ __launch_bounds__(256) void convert_w(
    const float* __restrict__ Wq, const float* __restrict__ Wk,
    const float* __restrict__ Wv, unsigned short* __restrict__ wt) {
  int idx = blockIdx.x * 256 + threadIdx.x;     // 0 .. 393215
  int m = idx >> 17;                            // which matrix
  int rem = idx & 131071;
  int k = rem >> 7;
  int n = rem & 127;
  const float* W = (m == 0) ? Wq : (m == 1) ? Wk : Wv;
  wt[(size_t)m * 131072 + (size_t)n * 1024 + k] = f2bf(W[(size_t)k * 128 + n]);
}

// ---------- kernel 2: QKV projection GEMM ----------
// C[16384,128] = x[16384,1024] @ W[1024,128] + b.  mode 0: Q (scaled 1/sqrt(128)),
// mode 1: K, mode 2: V written transposed as Vt[b][d][s].
__global__ __launch_bounds__(256) void qkv_gemm(
    const float* __restrict__ x, const unsigned short* __restrict__ wt_all,
    const float* __restrict__ bq, const float* __restrict__ bk,
    const float* __restrict__ bv,
    unsigned short* __restrict__ Qg, unsigned short* __restrict__ Kg,
    unsigned short* __restrict__ Vtg) {
  __shared__ unsigned short x_lds[128][40];   // +8 pad
  __shared__ unsigned short w_lds[128][40];
  const int tid = threadIdx.x;
  const int lane = tid & 63;
  const int w = tid >> 6;
  const int mode = blockIdx.y;
  const int m0 = blockIdx.x * 128;
  const unsigned short* wt = wt_all + (size_t)mode * 131072;
  const float* bias = (mode == 0) ? bq : (mode == 1) ? bk : bv;

  const int wr = (w >> 1) * 64;
  const int wc = (w & 1) * 64;
  const int lr = lane & 15;
  const int lk = (lane >> 4) * 8;

  f32x4 acc[4][4];
#pragma unroll
  for (int m = 0; m < 4; ++m)
#pragma unroll
    for (int n = 0; n < 4; ++n) acc[m][n] = (f32x4){0.f, 0.f, 0.f, 0.f};

  const int srow = tid >> 1;
  const int shalf = (tid & 1) * 16;

  for (int k0 = 0; k0 < 1024; k0 += 32) {
    __syncthreads();
    {
      // x tile: 128 rows x 32 cols f32 -> bf16
      const float4* s4 = (const float4*)(x + (size_t)(m0 + srow) * 1024 + k0 + shalf);
      float4 a = s4[0], b4 = s4[1], c4 = s4[2], d4 = s4[3];
      uint4 w0, w1;
      w0.x = pk2(a.x, a.y);  w0.y = pk2(a.z, a.w);
      w0.z = pk2(b4.x, b4.y); w0.w = pk2(b4.z, b4.w);
      w1.x = pk2(c4.x, c4.y); w1.y = pk2(c4.z, c4.w);
      w1.z = pk2(d4.x, d4.y); w1.w = pk2(d4.z, d4.w);
      *(uint4*)&x_lds[srow][shalf] = w0;
      *(uint4*)&x_lds[srow][shalf + 8] = w1;
      // W tile (already bf16, n-major): 128 n-rows x 32 k
      const uint4* ws4 = (const uint4*)(wt + (size_t)srow * 1024 + k0 + shalf);
      uint4 v0 = ws4[0], v1 = ws4[1];
      *(uint4*)&w_lds[srow][shalf] = v0;
      *(uint4*)&w_lds[srow][shalf + 8] = v1;
    }
    __syncthreads();
    bf16x8 af[4], bfr[4];
#pragma unroll
    for (int m = 0; m < 4; ++m) af[m] = *(const bf16x8*)&x_lds[wr + m * 16 + lr][lk];
#pragma unroll
    for (int n = 0; n < 4; ++n) bfr[n] = *(const bf16x8*)&w_lds[wc + n * 16 + lr][lk];
#pragma unroll
    for (int m = 0; m < 4; ++m)
#pragma unroll
      for (int n = 0; n < 4; ++n) acc[m][n] = MFMA16(af[m], bfr[n], acc[m][n]);
  }

  float bcol[4];
#pragma unroll
  for (int n = 0; n < 4; ++n) bcol[n] = bias[wc + n * 16 + lr];
#pragma unroll
  for (int m = 0; m < 4; ++m)
#pragma unroll
    for (int n = 0; n < 4; ++n)
#pragma unroll
      for (int r = 0; r < 4; ++r) {
        int grow = m0 + wr + m * 16 + (lane >> 4) * 4 + r;
        int col = wc + n * 16 + lr;
        float val = acc[m][n][r] + bcol[n];
        if (mode == 0) {
          val *= 0.08838834764831845f;  // 1/sqrt(128)
          Qg[(size_t)grow * 128 + col] = f2bf(val);
        } else if (mode == 1) {
          Kg[(size_t)grow * 128 + col] = f2bf(val);
        } else {
          int bb = grow >> 12, s = grow & 4095;
          Vtg[((size_t)bb * 128 + col) * 4096 + s] = f2bf(val);
        }
      }
}

// ---------- kernel 3: flash attention ----------
// block: 64 q-rows (4 waves x 16), KV tiles of 64. Q in regs, K/Vt staged in LDS.
__global__ __launch_bounds__(256) void attn_fwd(
    const unsigned short* __restrict__ Qg, const unsigned short* __restrict__ Kg,
    const unsigned short* __restrict__ Vtg, const float* __restrict__ pmask,
    float* __restrict__ out) {
  __shared__ unsigned short K_lds[64][136];
  __shared__ unsigned short V_lds[128][72];
  __shared__ unsigned short P_lds[4][16][72];
  const int tid = threadIdx.x;
  const int lane = tid & 63;
  const int w = tid >> 6;
  const int b = blockIdx.y;
  const int q0 = blockIdx.x * 64;
  const int lr = lane & 15;
  const int lg = lane >> 4;
  const int lk = lg * 8;

  bf16x8 qf[4];
  {
    const unsigned short* qp = Qg + ((size_t)b * 4096 + q0 + w * 16 + lr) * 128;
#pragma unroll
    for (int dc = 0; dc < 4; ++dc) qf[dc] = *(const bf16x8*)(qp + dc * 32 + lk);
  }
  float mrow[4], lsum[4];
  f32x4 o[8];
#pragma unroll
  for (int r = 0; r < 4; ++r) { mrow[r] = -1e30f; lsum[r] = 0.f; }
#pragma unroll
  for (int n = 0; n < 8; ++n) o[n] = (f32x4){0.f, 0.f, 0.f, 0.f};

  const int ntile = (q0 >> 6) + 1;
  for (int t = 0; t < ntile; ++t) {
    const int k0 = t * 64;
    __syncthreads();
    {
      // K tile: 64 rows x 128 d
      int kr = tid >> 2, seg = (tid & 3) * 32;
      const uint4* src = (const uint4*)(Kg + ((size_t)b * 4096 + k0 + kr) * 128 + seg);
      uint4 v0 = src[0], v1 = src[1], v2 = src[2], v3 = src[3];
      uint4* dst = (uint4*)&K_lds[kr][seg];
      dst[0] = v0; dst[1] = v1; dst[2] = v2; dst[3] = v3;
      // Vt tile: 128 d-rows x 64 k
      int d = tid >> 1, half = (tid & 1) * 32;
      const uint4* vs = (const uint4*)(Vtg + ((size_t)b * 128 + d) * 4096 + k0 + half);
      uint4 u0 = vs[0], u1 = vs[1], u2 = vs[2], u3 = vs[3];
      uint4* vdst = (uint4*)&V_lds[d][half];
      vdst[0] = u0; vdst[1] = u1; vdst[2] = u2; vdst[3] = u3;
    }
    __syncthreads();

    // S = Q K^T  (rows: q, cols: k)
    f32x4 sc[4];
#pragma unroll
    for (int f = 0; f < 4; ++f) {
      sc[f] = (f32x4){0.f, 0.f, 0.f, 0.f};
#pragma unroll
      for (int dc = 0; dc < 4; ++dc) {
        bf16x8 kf = *(const bf16x8*)&K_lds[f * 16 + lr][dc * 32 + lk];
        sc[f] = MFMA16(qf[dc], kf, sc[f]);
      }
    }
    float pmk[4];
#pragma unroll
    for (int f = 0; f < 4; ++f) pmk[f] = pmask[(size_t)b * 4096 + k0 + f * 16 + lr];

    float alpha[4];
    float p[4][4];
#pragma unroll
    for (int r = 0; r < 4; ++r) {
      const int qrow = q0 + w * 16 + lg * 4 + r;
      float mx = -1e30f;
#pragma unroll
      for (int f = 0; f < 4; ++f) {
        const int kc = k0 + f * 16 + lr;
        float s = (kc <= qrow && pmk[f] > 0.f) ? sc[f][r] : -1e30f;
        p[f][r] = s;
        mx = fmaxf(mx, s);
      }
      mx = fmaxf(mx, __shfl_xor(mx, 1));
      mx = fmaxf(mx, __shfl_xor(mx, 2));
      mx = fmaxf(mx, __shfl_xor(mx, 4));
      mx = fmaxf(mx, __shfl_xor(mx, 8));
      const float mnew = fmaxf(mrow[r], mx);
      alpha[r] = __expf(mrow[r] - mnew);
      mrow[r] = mnew;
      float sum = 0.f;
#pragma unroll
      for (int f = 0; f < 4; ++f) {
        float pv = (p[f][r] < -1e29f) ? 0.f : __expf(p[f][r] - mnew);
        p[f][r] = pv;
        sum += pv;
      }
      sum += __shfl_xor(sum, 1);
      sum += __shfl_xor(sum, 2);
      sum += __shfl_xor(sum, 4);
      sum += __shfl_xor(sum, 8);
      lsum[r] = lsum[r] * alpha[r] + sum;
    }
    // P -> per-wave LDS (bf16), rescale O
#pragma unroll
    for (int f = 0; f < 4; ++f)
#pragma unroll
      for (int r = 0; r < 4; ++r) P_lds[w][lg * 4 + r][f * 16 + lr] = f2bf(p[f][r]);
#pragma unroll
    for (int n = 0; n < 8; ++n)
#pragma unroll
      for (int r = 0; r < 4; ++r) o[n][r] *= alpha[r];
    __asm__ volatile("s_waitcnt lgkmcnt(0)" ::: "memory");
    // O += P V
#pragma unroll
    for (int kc = 0; kc < 2; ++kc) {
      bf16x8 pa = *(const bf16x8*)&P_lds[w][lr][kc * 32 + lk];
#pragma unroll
      for (int n = 0; n < 8; ++n) {
        bf16x8 vf = *(const bf16x8*)&V_lds[n * 16 + lr][kc * 32 + lk];
        o[n] = MFMA16(pa, vf, o[n]);
      }
    }
  }

#pragma unroll
  for (int r = 0; r < 4; ++r) {
    const int qrow = q0 + w * 16 + lg * 4 + r;
    const bool alive = pmask[(size_t)b * 4096 + qrow] > 0.f;
    const float inv = (alive && lsum[r] > 0.f) ? 1.f / lsum[r] : 0.f;
    float* op = out + ((size_t)b * 4096 + qrow) * 128;
#pragma unroll
    for (int n = 0; n < 8; ++n) op[n * 16 + lr] = o[n][r] * inv;
  }
}

extern "C" void kernel_launch(void* const* d_in, const int* in_sizes, int n_in,
                              void* d_out, int out_size, void* d_ws, size_t ws_size,
                              hipStream_t stream) {
  (void)in_sizes; (void)n_in; (void)out_size; (void)ws_size;
  const float* x  = (const float*)d_in[0];
  const float* pm = (const float*)d_in[1];
  const float* Wq = (const float*)d_in[2];
  const float* bq = (const float*)d_in[3];
  const float* Wk = (const float*)d_in[4];
  const float* bk = (const float*)d_in[5];
  const float* Wv = (const float*)d_in[6];
  const float* bv = (const float*)d_in[7];
  float* out = (float*)d_out;

  unsigned short* ws  = (unsigned short*)d_ws;
  unsigned short* wt  = ws;                    // 3*128*1024     = 393216 elems
  unsigned short* Qg  = ws + 393216;           // 16384*128      = 2097152
  unsigned short* Kg  = Qg + 2097152;
  unsigned short* Vtg = Kg + 2097152;          // total 13.4 MB of ws

  convert_w<<<1536, 256, 0, stream>>>(Wq, Wk, Wv, wt);
  qkv_gemm<<<dim3(128, 3), 256, 0, stream>>>(x, wt, bq, bk, bv, Qg, Kg, Vtg);
  attn_fwd<<<dim3(64, 4), 256, 0, stream>>>(Qg, Kg, Vtg, pm, out);
}

// Round 2
// 136.269 us; speedup vs baseline: 1.9055x; 1.9055x over previous
//
#include <hip/hip_runtime.h>
#include <hip/hip_bf16.h>
#include <cstdint>

typedef __bf16 bf16x8 __attribute__((ext_vector_type(8)));
typedef float f32x4 __attribute__((ext_vector_type(4)));

#define MFMA16(a, b, c) __builtin_amdgcn_mfma_f32_16x16x32_bf16((a), (b), (c), 0, 0, 0)

// ---------- helpers ----------
__device__ __forceinline__ unsigned short f2bf(float f) {
  union { float f; unsigned u; } v; v.f = f;
  unsigned u = v.u;
  u += 0x7fffu + ((u >> 16) & 1u);   // round-to-nearest-even (finite data only)
  return (unsigned short)(u >> 16);
}
__device__ __forceinline__ unsigned pk2(float a, float b) {
  return (unsigned)f2bf(a) | ((unsigned)f2bf(b) << 16);
}

// ---------- kernel 1: W [1024][128] f32 -> Wt bf16 [3][128][1024] (n-major) ----------
__global__ __launch_bounds__(256) void convert_w(
    const float* __restrict__ Wq, const float* __restrict__ Wk,
    const float* __restrict__ Wv, unsigned short* __restrict__ wt) {
  int idx = blockIdx.x * 256 + threadIdx.x;     // 0 .. 393215
  int m = idx >> 17;                            // which matrix
  int rem = idx & 131071;
  int k = rem >> 7;
  int n = rem & 127;
  const float* W = (m == 0) ? Wq : (m == 1) ? Wk : Wv;
  wt[(size_t)m * 131072 + (size_t)n * 1024 + k] = f2bf(W[(size_t)k * 128 + n]);
}

// ---------- kernel 2: QKV projection GEMM ----------
__global__ __launch_bounds__(256) void qkv_gemm(
    const float* __restrict__ x, const unsigned short* __restrict__ wt_all,
    const float* __restrict__ bq, const float* __restrict__ bk,
    const float* __restrict__ bv,
    unsigned short* __restrict__ Qg, unsigned short* __restrict__ Kg,
    unsigned short* __restrict__ Vtg) {
  __shared__ unsigned short x_lds[128][40];   // +8 pad
  __shared__ unsigned short w_lds[128][40];
  const int tid = threadIdx.x;
  const int lane = tid & 63;
  const int w = tid >> 6;
  const int mode = blockIdx.y;
  const int m0 = blockIdx.x * 128;
  const unsigned short* wt = wt_all + (size_t)mode * 131072;
  const float* bias = (mode == 0) ? bq : (mode == 1) ? bk : bv;

  const int wr = (w >> 1) * 64;
  const int wc = (w & 1) * 64;
  const int lr = lane & 15;
  const int lk = (lane >> 4) * 8;

  f32x4 acc[4][4];
#pragma unroll
  for (int m = 0; m < 4; ++m)
#pragma unroll
    for (int n = 0; n < 4; ++n) acc[m][n] = (f32x4){0.f, 0.f, 0.f, 0.f};

  const int srow = tid >> 1;
  const int shalf = (tid & 1) * 16;

  for (int k0 = 0; k0 < 1024; k0 += 32) {
    __syncthreads();
    {
      const float4* s4 = (const float4*)(x + (size_t)(m0 + srow) * 1024 + k0 + shalf);
      float4 a = s4[0], b4 = s4[1], c4 = s4[2], d4 = s4[3];
      uint4 w0, w1;
      w0.x = pk2(a.x, a.y);  w0.y = pk2(a.z, a.w);
      w0.z = pk2(b4.x, b4.y); w0.w = pk2(b4.z, b4.w);
      w1.x = pk2(c4.x, c4.y); w1.y = pk2(c4.z, c4.w);
      w1.z = pk2(d4.x, d4.y); w1.w = pk2(d4.z, d4.w);
      *(uint4*)&x_lds[srow][shalf] = w0;
      *(uint4*)&x_lds[srow][shalf + 8] = w1;
      const uint4* ws4 = (const uint4*)(wt + (size_t)srow * 1024 + k0 + shalf);
      uint4 v0 = ws4[0], v1 = ws4[1];
      *(uint4*)&w_lds[srow][shalf] = v0;
      *(uint4*)&w_lds[srow][shalf + 8] = v1;
    }
    __syncthreads();
    bf16x8 af[4], bfr[4];
#pragma unroll
    for (int m = 0; m < 4; ++m) af[m] = *(const bf16x8*)&x_lds[wr + m * 16 + lr][lk];
#pragma unroll
    for (int n = 0; n < 4; ++n) bfr[n] = *(const bf16x8*)&w_lds[wc + n * 16 + lr][lk];
#pragma unroll
    for (int m = 0; m < 4; ++m)
#pragma unroll
      for (int n = 0; n < 4; ++n) acc[m][n] = MFMA16(af[m], bfr[n], acc[m][n]);
  }

  float bcol[4];
#pragma unroll
  for (int n = 0; n < 4; ++n) bcol[n] = bias[wc + n * 16 + lr];
#pragma unroll
  for (int m = 0; m < 4; ++m)
#pragma unroll
    for (int n = 0; n < 4; ++n)
#pragma unroll
      for (int r = 0; r < 4; ++r) {
        int grow = m0 + wr + m * 16 + (lane >> 4) * 4 + r;
        int col = wc + n * 16 + lr;
        float val = acc[m][n][r] + bcol[n];
        if (mode == 0) {
          val *= 0.08838834764831845f;  // 1/sqrt(128)
          Qg[(size_t)grow * 128 + col] = f2bf(val);
        } else if (mode == 1) {
          Kg[(size_t)grow * 128 + col] = f2bf(val);
        } else {
          int bb = grow >> 12, s = grow & 4095;
          Vtg[((size_t)bb * 128 + col) * 4096 + s] = f2bf(val);
        }
      }
}

// ---------- shared attention tile body ----------
// Processes KV tiles [tstart, tend) for 64 q-rows starting at q0 (batch b).
// State: qf (regs), mrow/lsum/o. Returns via references.
struct AttnLds {
  unsigned short K_lds[64][136];
  unsigned short V_lds[128][72];
  unsigned short P_lds[4][16][72];
};

__device__ __forceinline__ void attn_tiles(
    AttnLds& S, const unsigned short* __restrict__ Kg,
    const unsigned short* __restrict__ Vtg, const float* __restrict__ pmask,
    int b, int q0, int tstart, int tend,
    const bf16x8 (&qf)[4], float (&mrow)[4], float (&lsum)[4], f32x4 (&o)[8]) {
  const int tid = threadIdx.x;
  const int lane = tid & 63;
  const int w = tid >> 6;
  const int lr = lane & 15;
  const int lg = lane >> 4;
  const int lk = lg * 8;

  for (int t = tstart; t < tend; ++t) {
    const int k0 = t * 64;
    __syncthreads();
    {
      int kr = tid >> 2, seg = (tid & 3) * 32;
      const uint4* src = (const uint4*)(Kg + ((size_t)b * 4096 + k0 + kr) * 128 + seg);
      uint4 v0 = src[0], v1 = src[1], v2 = src[2], v3 = src[3];
      uint4* dst = (uint4*)&S.K_lds[kr][seg];
      dst[0] = v0; dst[1] = v1; dst[2] = v2; dst[3] = v3;
      int d = tid >> 1, half = (tid & 1) * 32;
      const uint4* vs = (const uint4*)(Vtg + ((size_t)b * 128 + d) * 4096 + k0 + half);
      uint4 u0 = vs[0], u1 = vs[1], u2 = vs[2], u3 = vs[3];
      uint4* vdst = (uint4*)&S.V_lds[d][half];
      vdst[0] = u0; vdst[1] = u1; vdst[2] = u2; vdst[3] = u3;
    }
    __syncthreads();

    f32x4 sc[4];
#pragma unroll
    for (int f = 0; f < 4; ++f) {
      sc[f] = (f32x4){0.f, 0.f, 0.f, 0.f};
#pragma unroll
      for (int dc = 0; dc < 4; ++dc) {
        bf16x8 kf = *(const bf16x8*)&S.K_lds[f * 16 + lr][dc * 32 + lk];
        sc[f] = MFMA16(qf[dc], kf, sc[f]);
      }
    }
    float pmk[4];
#pragma unroll
    for (int f = 0; f < 4; ++f) pmk[f] = pmask[(size_t)b * 4096 + k0 + f * 16 + lr];

    float alpha[4];
    float p[4][4];
#pragma unroll
    for (int r = 0; r < 4; ++r) {
      const int qrow = q0 + w * 16 + lg * 4 + r;
      float mx = -1e30f;
#pragma unroll
      for (int f = 0; f < 4; ++f) {
        const int kc = k0 + f * 16 + lr;
        float s = (kc <= qrow && pmk[f] > 0.f) ? sc[f][r] : -1e30f;
        p[f][r] = s;
        mx = fmaxf(mx, s);
      }
      mx = fmaxf(mx, __shfl_xor(mx, 1));
      mx = fmaxf(mx, __shfl_xor(mx, 2));
      mx = fmaxf(mx, __shfl_xor(mx, 4));
      mx = fmaxf(mx, __shfl_xor(mx, 8));
      const float mnew = fmaxf(mrow[r], mx);
      alpha[r] = __expf(mrow[r] - mnew);
      mrow[r] = mnew;
      float sum = 0.f;
#pragma unroll
      for (int f = 0; f < 4; ++f) {
        float pv = (p[f][r] < -1e29f) ? 0.f : __expf(p[f][r] - mnew);
        p[f][r] = pv;
        sum += pv;
      }
      sum += __shfl_xor(sum, 1);
      sum += __shfl_xor(sum, 2);
      sum += __shfl_xor(sum, 4);
      sum += __shfl_xor(sum, 8);
      lsum[r] = lsum[r] * alpha[r] + sum;
    }
#pragma unroll
    for (int f = 0; f < 4; ++f)
#pragma unroll
      for (int r = 0; r < 4; ++r) S.P_lds[w][lg * 4 + r][f * 16 + lr] = f2bf(p[f][r]);
#pragma unroll
    for (int n = 0; n < 8; ++n)
#pragma unroll
      for (int r = 0; r < 4; ++r) o[n][r] *= alpha[r];
    __asm__ volatile("s_waitcnt lgkmcnt(0)" ::: "memory");
#pragma unroll
    for (int kc = 0; kc < 2; ++kc) {
      bf16x8 pa = *(const bf16x8*)&S.P_lds[w][lr][kc * 32 + lk];
#pragma unroll
      for (int n = 0; n < 8; ++n) {
        bf16x8 vf = *(const bf16x8*)&S.V_lds[n * 16 + lr][kc * 32 + lk];
        o[n] = MFMA16(pa, vf, o[n]);
      }
    }
  }
}

// ---------- kernel 3a: fallback monolithic flash attention ----------
__global__ __launch_bounds__(256) void attn_fwd(
    const unsigned short* __restrict__ Qg, const unsigned short* __restrict__ Kg,
    const unsigned short* __restrict__ Vtg, const float* __restrict__ pmask,
    float* __restrict__ out) {
  __shared__ AttnLds S;
  const int tid = threadIdx.x;
  const int lane = tid & 63;
  const int w = tid >> 6;
  const int b = blockIdx.y;
  const int q0 = blockIdx.x * 64;
  const int lr = lane & 15;
  const int lg = lane >> 4;
  const int lk = lg * 8;

  bf16x8 qf[4];
  {
    const unsigned short* qp = Qg + ((size_t)b * 4096 + q0 + w * 16 + lr) * 128;
#pragma unroll
    for (int dc = 0; dc < 4; ++dc) qf[dc] = *(const bf16x8*)(qp + dc * 32 + lk);
  }
  float mrow[4], lsum[4];
  f32x4 o[8];
#pragma unroll
  for (int r = 0; r < 4; ++r) { mrow[r] = -1e30f; lsum[r] = 0.f; }
#pragma unroll
  for (int n = 0; n < 8; ++n) o[n] = (f32x4){0.f, 0.f, 0.f, 0.f};

  attn_tiles(S, Kg, Vtg, pmask, b, q0, 0, (q0 >> 6) + 1, qf, mrow, lsum, o);

#pragma unroll
  for (int r = 0; r < 4; ++r) {
    const int qrow = q0 + w * 16 + lg * 4 + r;
    const bool alive = pmask[(size_t)b * 4096 + qrow] > 0.f;
    const float inv = (alive && lsum[r] > 0.f) ? 1.f / lsum[r] : 0.f;
    float* op = out + ((size_t)b * 4096 + qrow) * 128;
#pragma unroll
    for (int n = 0; n < 8; ++n) op[n * 16 + lr] = o[n][r] * inv;
  }
}

// ---------- kernel 3b: split-KV flash attention (chunks of 16 KV tiles) ----------
// Per batch 160 work items: (qb, c) with nch(qb)=ceil((qb+1)/16).
__global__ __launch_bounds__(256) void attn_split(
    const unsigned short* __restrict__ Qg, const unsigned short* __restrict__ Kg,
    const unsigned short* __restrict__ Vtg, const float* __restrict__ pmask,
    float* __restrict__ out, float* __restrict__ o_part, float* __restrict__ ml_part) {
  __shared__ AttnLds S;
  const int tid = threadIdx.x;
  const int lane = tid & 63;
  const int w = tid >> 6;
  const int b = blockIdx.y;
  const int idx = blockIdx.x;
  int qb, c, nch;
  if (idx < 16)      { qb = idx;               c = 0;           nch = 1; }
  else if (idx < 48) { int t = idx - 16; qb = 16 + (t >> 1); c = t & 1;  nch = 2; }
  else if (idx < 96) { int t = idx - 48; qb = 32 + t / 3;    c = t % 3;  nch = 3; }
  else               { int t = idx - 96; qb = 48 + (t >> 2); c = t & 3;  nch = 4; }
  const int q0 = qb * 64;
  const int tstart = c * 16;
  const int tend = min((c + 1) * 16, qb + 1);
  const int lr = lane & 15;
  const int lg = lane >> 4;
  const int lk = lg * 8;

  bf16x8 qf[4];
  {
    const unsigned short* qp = Qg + ((size_t)b * 4096 + q0 + w * 16 + lr) * 128;
#pragma unroll
    for (int dc = 0; dc < 4; ++dc) qf[dc] = *(const bf16x8*)(qp + dc * 32 + lk);
  }
  float mrow[4], lsum[4];
  f32x4 o[8];
#pragma unroll
  for (int r = 0; r < 4; ++r) { mrow[r] = -1e30f; lsum[r] = 0.f; }
#pragma unroll
  for (int n = 0; n < 8; ++n) o[n] = (f32x4){0.f, 0.f, 0.f, 0.f};

  attn_tiles(S, Kg, Vtg, pmask, b, q0, tstart, tend, qf, mrow, lsum, o);

  if (nch == 1) {
#pragma unroll
    for (int r = 0; r < 4; ++r) {
      const int qrow = q0 + w * 16 + lg * 4 + r;
      const bool alive = pmask[(size_t)b * 4096 + qrow] > 0.f;
      const float inv = (alive && lsum[r] > 0.f) ? 1.f / lsum[r] : 0.f;
      float* op = out + ((size_t)b * 4096 + qrow) * 128;
#pragma unroll
      for (int n = 0; n < 8; ++n) op[n * 16 + lr] = o[n][r] * inv;
    }
  } else {
    const int part = (b * 64 + qb) * 4 + c;
#pragma unroll
    for (int r = 0; r < 4; ++r) {
      const int row = w * 16 + lg * 4 + r;
      float* op = o_part + ((size_t)part * 64 + row) * 128;
#pragma unroll
      for (int n = 0; n < 8; ++n) op[n * 16 + lr] = o[n][r];
      if (lr == 0) {
        float* mp = ml_part + ((size_t)part * 64 + row) * 2;
        mp[0] = mrow[r];
        mp[1] = lsum[r];
      }
    }
  }
}

// ---------- kernel 3c: combine partials (qb >= 16) ----------
__global__ __launch_bounds__(256) void attn_combine(
    const float* __restrict__ o_part, const float* __restrict__ ml_part,
    const float* __restrict__ pmask, float* __restrict__ out) {
  const int tid = threadIdx.x;
  const int lane = tid & 63;
  const int w = tid >> 6;
  const int g = blockIdx.x * 4 + w;     // 0 .. 12287
  const int b = g / 3072;
  const int rem = g % 3072;
  const int qb = 16 + (rem >> 6);
  const int row = rem & 63;
  const int qrow = qb * 64 + row;
  const int nch = (qb >> 4) + 1;        // 2..4
  const int pbase = (b * 64 + qb) * 4;

  float m[4], l[4];
  float M = -1e30f;
  for (int c = 0; c < nch; ++c) {
    const float* mp = ml_part + ((size_t)(pbase + c) * 64 + row) * 2;
    m[c] = mp[0];
    l[c] = mp[1];
    M = fmaxf(M, m[c]);
  }
  float L = 0.f, wgt[4];
  for (int c = 0; c < nch; ++c) {
    wgt[c] = __expf(m[c] - M);
    L += wgt[c] * l[c];
  }
  float2 acc = {0.f, 0.f};
  for (int c = 0; c < nch; ++c) {
    const float2 v = *(const float2*)(o_part + ((size_t)(pbase + c) * 64 + row) * 128 + lane * 2);
    acc.x += wgt[c] * v.x;
    acc.y += wgt[c] * v.y;
  }
  const bool alive = pmask[(size_t)b * 4096 + qrow] > 0.f;
  const float inv = (alive && L > 0.f) ? 1.f / L : 0.f;
  float2* op = (float2*)(out + ((size_t)b * 4096 + qrow) * 128);
  op[lane] = make_float2(acc.x * inv, acc.y * inv);
}

extern "C" void kernel_launch(void* const* d_in, const int* in_sizes, int n_in,
                              void* d_out, int out_size, void* d_ws, size_t ws_size,
                              hipStream_t stream) {
  (void)in_sizes; (void)n_in; (void)out_size;
  const float* x  = (const float*)d_in[0];
  const float* pm = (const float*)d_in[1];
  const float* Wq = (const float*)d_in[2];
  const float* bq = (const float*)d_in[3];
  const float* Wk = (const float*)d_in[4];
  const float* bk = (const float*)d_in[5];
  const float* Wv = (const float*)d_in[6];
  const float* bv = (const float*)d_in[7];
  float* out = (float*)d_out;

  unsigned short* ws  = (unsigned short*)d_ws;
  unsigned short* wt  = ws;                    // 3*128*1024   = 393216 shorts
  unsigned short* Qg  = ws + 393216;           // 16384*128    = 2097152
  unsigned short* Kg  = Qg + 2097152;
  unsigned short* Vtg = Kg + 2097152;          // bf16 total 13.37 MB
  float* o_part  = (float*)(ws + 6684672);     // 1024 parts * 64 rows * 128 = 33.55 MB
  float* ml_part = o_part + 8388608;           // 1024 * 64 * 2 = 0.52 MB
  const size_t WS_NEED = 13369344u + (8388608u + 131072u) * 4u;  // 47.45 MB

  convert_w<<<1536, 256, 0, stream>>>(Wq, Wk, Wv, wt);
  qkv_gemm<<<dim3(128, 3), 256, 0, stream>>>(x, wt, bq, bk, bv, Qg, Kg, Vtg);
  if (ws_size >= WS_NEED) {
    attn_split<<<dim3(160, 4), 256, 0, stream>>>(Qg, Kg, Vtg, pm, out, o_part, ml_part);
    attn_combine<<<3072, 256, 0, stream>>>(o_part, ml_part, pm, out);
  } else {
    attn_fwd<<<dim3(64, 4), 256, 0, stream>>>(Qg, Kg, Vtg, pm, out);
  }
}